// Round 37
// baseline (54.003 us; speedup 1.0000x reference)
//
#include <hip/hip_runtime.h>
#include <hip/hip_bf16.h>
#include <cstdint>

// MoE MLP fused forward. T=512, K=2 slots, E=32, H=512, I=512 (2I=1024).
// DEVICE DTYPES (probe-verified r20-r22): f32 tensors with bf16-exact values;
// output = full 262144 x f32 at d_out.
//
// r35 51.1us (swizzled row-major glds staging, verified). r27/r32/r36
// concurrency levers all null -> the residual is the barrier-drain count:
// 4 serial {stage, full-vmcnt-drain} phases per group, compute negligible.
// r37: Kc 128 -> 256. mlp1 Bs 64KB + As 32KB (2 chunks, 2 drains, 512 thr);
// mlp2 Bs 64KB + As-bf16 16KB (2 chunks, 256 thr). Same swizzle algebra
// (64-unit rows, unit ^= row&7 on both glds source and ds_read slot) and
// r35-verified geometry/epilogues. 4 launches, no atomics -> deterministic.

#define MOE_E 32
#define MOE_H 512
#define MOE_I 512
#define MOE_2I 1024
#define MOE_CAP 1024

typedef __attribute__((ext_vector_type(8))) short s16x8;   // 8 bf16
typedef __attribute__((ext_vector_type(4))) float f32x4;   // 4 f32 acc
typedef unsigned short u16;

#define GLDS16(g, l)  __builtin_amdgcn_global_load_lds(                        \
    (const __attribute__((address_space(1))) unsigned int*)(g),                \
    (__attribute__((address_space(3))) unsigned int*)(l), 16, 0, 0)

__device__ __forceinline__ s16x8 pack8(float4 f0, float4 f1) {
    union { unsigned int u[4]; s16x8 v; } r;
    r.u[0] = (__float_as_uint(f0.y) & 0xFFFF0000u) | (__float_as_uint(f0.x) >> 16);
    r.u[1] = (__float_as_uint(f0.w) & 0xFFFF0000u) | (__float_as_uint(f0.z) >> 16);
    r.u[2] = (__float_as_uint(f1.y) & 0xFFFF0000u) | (__float_as_uint(f1.x) >> 16);
    r.u[3] = (__float_as_uint(f1.w) & 0xFFFF0000u) | (__float_as_uint(f1.z) >> 16);
    return r.v;
}

__device__ __forceinline__ u16 f2bf_rtne(float f) {
    const unsigned int u = __float_as_uint(f);
    return (u16)((u + 0x7FFFu + ((u >> 16) & 1u)) >> 16);
}

// ---------------- route: bucket (token,slot) pairs by expert ----------------
__global__ __launch_bounds__(1024) void moe_route(const int* __restrict__ idx,
                                                  int* __restrict__ cnt,
                                                  int* __restrict__ lists) {
    __shared__ int scnt[MOE_E];
    const int p = threadIdx.x;
    if (p < MOE_E) scnt[p] = 0;
    __syncthreads();
    int e = idx[p];
    e = (e < 0) ? 0 : (e > MOE_E - 1 ? MOE_E - 1 : e);
    const int pos = atomicAdd(&scnt[e], 1);
    lists[e * MOE_CAP + pos] = p;
    __syncthreads();
    if (p < MOE_E) cnt[p] = scnt[p];
}

// ---- mlp1 + swiglu (MFMA, glds, Kc=256): grid (16, E), 512 thr = 8 waves. ----
// Wave w: cols (w&3)*16 + n16; m-tile w>>2. Bs [64r][64u], As [32r][64u]
// (16B units, unit ^= row&7 on glds source and ds_read slot). 2 K-chunks.
// Epilogue: bias + shfl_xor swiglu -> hbuf bf16 (h col = cg>>1).
__global__ __launch_bounds__(512) void moe_mlp1(
    const float* __restrict__ x, const float* __restrict__ w1,
    const float* __restrict__ b1, const int* __restrict__ cnt,
    const int* __restrict__ lists, u16* __restrict__ hbuf) {
    __shared__ float Bs[4096 * 4];   // 64 KB
    __shared__ float As[2048 * 4];   // 32 KB
    const int e = blockIdx.y;
    const int ne = cnt[e];
    if (ne == 0) return;
    const int tid   = threadIdx.x;           // 0..511
    const int lane  = tid & 63;
    const int wave  = tid >> 6;              // 0..7
    const int n16   = lane & 15;
    const int k8    = lane >> 4;
    const int mtile = wave >> 2;             // 0..1
    const int* lst = lists + e * MOE_CAP;
    const int cg = blockIdx.x * 64 + (wave & 3) * 16 + n16;   // w1 row 0..1023
    const float bv = b1[e * MOE_2I + cg];
    const float* wbase = w1 + ((size_t)e * MOE_2I + blockIdx.x * 64) * MOE_H;

    for (int g0 = 0; g0 < ne; g0 += 32) {
        f32x4 acc = {0.f, 0.f, 0.f, 0.f};    // token rows mtile*16 + n16
        for (int kc = 0; kc < 2; ++kc) {
            __syncthreads();   // prior chunk's LDS readers done
            // Bs: 4096 units, 8 glds/thread. Instruction j = full row j*8+wave
            // (64 lanes = 64 units = 1KB contiguous, permuted by ^(r&7)).
            #pragma unroll
            for (int j = 0; j < 8; ++j) {
                const int r = j * 8 + wave;    // 0..63  (u = r*64 + lane)
                const int c = lane;            // 0..63
                GLDS16(wbase + (size_t)r * MOE_H + kc * 256 + 4 * (c ^ (r & 7)),
                       Bs + (size_t)r * 256);
            }
            // As: 2048 units, 4 glds/thread. Instruction j = token row j*8+wave.
            #pragma unroll
            for (int j = 0; j < 4; ++j) {
                const int r = j * 8 + wave;    // 0..31
                const int c = lane;
                const int pm = lst[min(g0 + r, ne - 1)];
                GLDS16(x + (size_t)(pm >> 1) * MOE_H + kc * 256 + 4 * (c ^ (r & 7)),
                       As + (size_t)r * 256);
            }
            __syncthreads();   // vmcnt drain + barrier: tiles visible

            #pragma unroll
            for (int ks = 0; ks < 8; ++ks) {
                const int c0 = ks * 8 + k8 * 2;            // even unit 0..62
                const int Rb = (wave & 3) * 16 + n16;
                const float4 B0 = *(const float4*)(Bs + 4 * (Rb * 64 + ((c0    ) ^ (Rb & 7))));
                const float4 B1 = *(const float4*)(Bs + 4 * (Rb * 64 + ((c0 + 1) ^ (Rb & 7))));
                const int Ra = mtile * 16 + n16;
                const float4 A0 = *(const float4*)(As + 4 * (Ra * 64 + ((c0    ) ^ (Ra & 7))));
                const float4 A1 = *(const float4*)(As + 4 * (Ra * 64 + ((c0 + 1) ^ (Ra & 7))));
                acc = __builtin_amdgcn_mfma_f32_16x16x32_bf16(
                    pack8(A0, A1), pack8(B0, B1), acc, 0, 0, 0);
            }
        }
        // ---- epilogue: bias + swiglu (even cg = gate, odd = linear) ----
        #pragma unroll
        for (int q = 0; q < 4; ++q) {
            const float val = acc[q] + bv;
            const float other = __shfl_xor(val, 1);       // partner column
            const int mrow = g0 + mtile * 16 + k8 * 4 + q;  // D: row=(l>>4)*4+q
            if ((cg & 1) == 0 && mrow < ne) {
                const float g = fminf(val, 7.0f);
                const float l = fminf(fmaxf(other, -7.0f), 7.0f);
                const float h = g / (1.0f + expf(-1.702f * g)) * (l + 1.0f);
                const int p = lst[mrow];
                hbuf[(size_t)p * MOE_I + (cg >> 1)] = f2bf_rtne(h);
            }
        }
    }
}

// ---- mlp2 (MFMA, glds, Kc=256): grid (8, E), 256 thr. A = hbuf bf16. ----
// Bs [64r][64u] f32; As bf16 [32r][32u] (16B units = 8 bf16). 2 K-chunks.
__global__ __launch_bounds__(256) void moe_mlp2(
    const u16* __restrict__ hbuf, const float* __restrict__ w2,
    const float* __restrict__ b2, const int* __restrict__ cnt,
    const int* __restrict__ lists, float* __restrict__ po) {
    __shared__ float Bs[4096 * 4];   // 64 KB
    __shared__ u16 As[1024 * 8];     // 16 KB
    const int e = blockIdx.y;
    const int ne = cnt[e];
    if (ne == 0) return;
    const int tid  = threadIdx.x;
    const int lane = tid & 63;
    const int wave = tid >> 6;
    const int n16  = lane & 15;
    const int k8   = lane >> 4;
    const int* lst = lists + e * MOE_CAP;
    const int c = blockIdx.x * 64 + wave * 16 + n16;       // out col 0..511
    const float bv = b2[e * MOE_H + c];
    const float* wbase = w2 + ((size_t)e * MOE_H + blockIdx.x * 64) * MOE_I;

    for (int g0 = 0; g0 < ne; g0 += 32) {
        f32x4 acc0 = {0.f, 0.f, 0.f, 0.f};
        f32x4 acc1 = {0.f, 0.f, 0.f, 0.f};
        for (int kc = 0; kc < 2; ++kc) {
            __syncthreads();
            // Bs: 4096 units, 16 glds/thread. Instruction j = full row j*4+wave.
            #pragma unroll
            for (int j = 0; j < 16; ++j) {
                const int r = j * 4 + wave;    // 0..63
                const int cu = lane;           // 0..63
                GLDS16(wbase + (size_t)r * MOE_I + kc * 256 + 4 * (cu ^ (r & 7)),
                       Bs + (size_t)r * 256);
            }
            // As bf16: 1024 units (u = r*32 + (cu^(r&7))), 4 glds/thread.
            #pragma unroll
            for (int j = 0; j < 4; ++j) {
                const int u = (j * 4 + wave) * 64 + lane;
                const int r = u >> 5;          // 0..31
                const int cu = u & 31;
                const int pm = lst[min(g0 + r, ne - 1)];
                GLDS16(hbuf + (size_t)pm * MOE_I + kc * 256 + 8 * (cu ^ (r & 7)),
                       As + (size_t)(j * 4 + wave) * 512);
            }
            __syncthreads();

            #pragma unroll
            for (int ks = 0; ks < 8; ++ks) {
                const int c0 = ks * 8 + k8 * 2;
                const int Rb = wave * 16 + n16;
                const float4 B0 = *(const float4*)(Bs + 4 * (Rb * 64 + ((c0    ) ^ (Rb & 7))));
                const float4 B1 = *(const float4*)(Bs + 4 * (Rb * 64 + ((c0 + 1) ^ (Rb & 7))));
                const s16x8 BF = pack8(B0, B1);
                const int cA = ks * 4 + k8;                // bf16 unit 0..31
                const int Ra0 = n16;
                const int Ra1 = 16 + n16;
                const s16x8 A0 = *(const s16x8*)(As + (size_t)(Ra0 * 32 + (cA ^ (Ra0 & 7))) * 8);
                const s16x8 A1 = *(const s16x8*)(As + (size_t)(Ra1 * 32 + (cA ^ (Ra1 & 7))) * 8);
                acc0 = __builtin_amdgcn_mfma_f32_16x16x32_bf16(A0, BF, acc0, 0, 0, 0);
                acc1 = __builtin_amdgcn_mfma_f32_16x16x32_bf16(A1, BF, acc1, 0, 0, 0);
            }
        }
        #pragma unroll
        for (int tile = 0; tile < 2; ++tile) {
            const f32x4 acc = tile ? acc1 : acc0;
            #pragma unroll
            for (int q = 0; q < 4; ++q) {
                const int mrow = g0 + tile * 16 + k8 * 4 + q;
                if (mrow < ne) {
                    const int p = lst[mrow];
                    po[(size_t)p * MOE_H + c] = acc[q] + bv;
                }
            }
        }
    }
}

// ---- combine: out[t,c] = ew0*po[2t,c] + ew1*po[2t+1,c] ----
__global__ __launch_bounds__(256) void MoEMLPFused_74191265071207_kernel(
    const float* __restrict__ po, const float* __restrict__ ew,
    float* __restrict__ out) {
    const int o = blockIdx.x * 256 + threadIdx.x;   // < 262144
    const int t = o >> 9;
    const int c = o & 511;
    out[o] = ew[2 * t + 0] * po[(size_t)(2 * t + 0) * MOE_H + c]
           + ew[2 * t + 1] * po[(size_t)(2 * t + 1) * MOE_H + c];
}

extern "C" void kernel_launch(void* const* d_in, const int* in_sizes, int n_in,
                              void* d_out, int out_size, void* d_ws, size_t ws_size,
                              hipStream_t stream) {
    const float* x   = (const float*)d_in[0];
    const int*   idx = (const int*)d_in[1];
    const float* ew  = (const float*)d_in[2];
    const float* w1  = (const float*)d_in[3];
    const float* b1  = (const float*)d_in[4];
    const float* w2  = (const float*)d_in[5];
    const float* b2  = (const float*)d_in[6];
    float* out = (float*)d_out;

    // ws: cnt 256B | lists 128KB | hbuf bf16 1MB | po f32 2MB  (~3.2MB)
    char* ws = (char*)d_ws;
    int* cnt   = (int*)ws;
    int* lists = (int*)(ws + 256);
    u16* hbuf  = (u16*)(ws + 256 + MOE_E * MOE_CAP * 4);
    float* po  = (float*)((char*)hbuf + (size_t)MOE_CAP * MOE_I * 2);

    moe_route<<<1, 1024, 0, stream>>>(idx, cnt, lists);
    moe_mlp1<<<dim3(16, MOE_E), 512, 0, stream>>>(x, w1, b1, cnt, lists, hbuf);
    moe_mlp2<<<dim3(8, MOE_E), 256, 0, stream>>>(hbuf, w2, b2, cnt, lists, po);
    MoEMLPFused_74191265071207_kernel<<<(512 * MOE_H) / 256, 256, 0, stream>>>(
        po, ew, out);
}

// Round 38
// 51.198 us; speedup vs baseline: 1.0548x; 1.0548x over previous
//
#include <hip/hip_runtime.h>
#include <hip/hip_bf16.h>
#include <cstdint>

// MoE MLP fused forward. T=512, K=2 slots, E=32, H=512, I=512 (2I=1024).
// DEVICE DTYPES (probe-verified r20-r22): f32 tensors with bf16-exact values
// (harness widens bf16<->f32 at the device boundary); output = the FULL
// 262144 x f32 buffer at d_out.
//
// FINAL (r38 = r36, the empirical optimum at 50.99us, verified PASS).
// Ladder: 266us (first correct, per-token) -> 157 (expert-grouped LDS) ->
// 68 (MFMA) -> 59 (glds staging) -> 51 (sequential+XOR-swizzled staging).
// Falsified levers: waves/blocks/K-split x2 (null x3), prefetch/launch
// bounds/K-perm/LDS-seq (null x4), drain-count/2 via Kc=256 (regression).
// Remaining ~2x vs the ~25-30us traffic floor is the cold-HBM staging rate
// under phase-synchronized block starts; would need a persistent
// producer-consumer schedule (new sync template) to attack.

#define MOE_E 32
#define MOE_H 512
#define MOE_I 512
#define MOE_2I 1024
#define MOE_CAP 1024

typedef __attribute__((ext_vector_type(8))) short s16x8;   // 8 bf16
typedef __attribute__((ext_vector_type(4))) float f32x4;   // 4 f32 acc
typedef unsigned short u16;

#define GLDS16(g, l)  __builtin_amdgcn_global_load_lds(                        \
    (const __attribute__((address_space(1))) unsigned int*)(g),                \
    (__attribute__((address_space(3))) unsigned int*)(l), 16, 0, 0)

__device__ __forceinline__ s16x8 pack8(float4 f0, float4 f1) {
    union { unsigned int u[4]; s16x8 v; } r;
    r.u[0] = (__float_as_uint(f0.y) & 0xFFFF0000u) | (__float_as_uint(f0.x) >> 16);
    r.u[1] = (__float_as_uint(f0.w) & 0xFFFF0000u) | (__float_as_uint(f0.z) >> 16);
    r.u[2] = (__float_as_uint(f1.y) & 0xFFFF0000u) | (__float_as_uint(f1.x) >> 16);
    r.u[3] = (__float_as_uint(f1.w) & 0xFFFF0000u) | (__float_as_uint(f1.z) >> 16);
    return r.v;
}

__device__ __forceinline__ u16 f2bf_rtne(float f) {
    const unsigned int u = __float_as_uint(f);
    return (u16)((u + 0x7FFFu + ((u >> 16) & 1u)) >> 16);
}

// ---------------- route: bucket (token,slot) pairs by expert ----------------
__global__ __launch_bounds__(1024) void moe_route(const int* __restrict__ idx,
                                                  int* __restrict__ cnt,
                                                  int* __restrict__ lists) {
    __shared__ int scnt[MOE_E];
    const int p = threadIdx.x;
    if (p < MOE_E) scnt[p] = 0;
    __syncthreads();
    int e = idx[p];
    e = (e < 0) ? 0 : (e > MOE_E - 1 ? MOE_E - 1 : e);
    const int pos = atomicAdd(&scnt[e], 1);
    lists[e * MOE_CAP + pos] = p;
    __syncthreads();
    if (p < MOE_E) cnt[p] = scnt[p];
}

// ---- mlp1 + swiglu (MFMA, glds, full-K): grid (16, E), 512 thr = 8 waves. ----
// Wave w: cols (w&3)*16 + n16; m-tile w>>2 (token rows (w>>2)*16 + n16).
// Tiles: Bs row-major [64r][32u], As [32r][32u] (16B units, unit ^= row&7;
// write side permutes the per-lane GLOBAL source within each row's 512B).
// Epilogue: bias + shfl_xor swiglu -> hbuf bf16 (h col = cg>>1).
__global__ __launch_bounds__(512) void moe_mlp1(
    const float* __restrict__ x, const float* __restrict__ w1,
    const float* __restrict__ b1, const int* __restrict__ cnt,
    const int* __restrict__ lists, u16* __restrict__ hbuf) {
    __shared__ float Bs[2048 * 4];   // 32 KB
    __shared__ float As[1024 * 4];   // 16 KB
    const int e = blockIdx.y;
    const int ne = cnt[e];
    if (ne == 0) return;
    const int tid   = threadIdx.x;           // 0..511
    const int lane  = tid & 63;
    const int wave  = tid >> 6;              // 0..7
    const int n16   = lane & 15;
    const int k8    = lane >> 4;
    const int mtile = wave >> 2;             // 0..1
    const int* lst = lists + e * MOE_CAP;
    const int cg = blockIdx.x * 64 + (wave & 3) * 16 + n16;   // w1 row 0..1023
    const float bv = b1[e * MOE_2I + cg];
    const float* wbase = w1 + ((size_t)e * MOE_2I + blockIdx.x * 64) * MOE_H;

    for (int g0 = 0; g0 < ne; g0 += 32) {
        f32x4 acc = {0.f, 0.f, 0.f, 0.f};    // token rows mtile*16 + n16
        for (int kc = 0; kc < 4; ++kc) {
            __syncthreads();   // prior chunk's LDS readers done
            // Bs: 2048 units, 4 glds/thread. slot u = r*32 + (c^(r&7)).
            #pragma unroll
            for (int j = 0; j < 4; ++j) {
                const int u = (j * 8 + wave) * 64 + lane;
                const int r = u >> 5;          // 0..63
                const int c = u & 31;
                GLDS16(wbase + (size_t)r * MOE_H + kc * 128 + 4 * (c ^ (r & 7)),
                       Bs + (size_t)(j * 8 + wave) * 256);
            }
            // As: 1024 units, 2 glds/thread. r = token row 0..31.
            #pragma unroll
            for (int j = 0; j < 2; ++j) {
                const int u = (j * 8 + wave) * 64 + lane;
                const int r = u >> 5;          // 0..31
                const int c = u & 31;
                const int pm = lst[min(g0 + r, ne - 1)];
                GLDS16(x + (size_t)(pm >> 1) * MOE_H + kc * 128 + 4 * (c ^ (r & 7)),
                       As + (size_t)(j * 8 + wave) * 256);
            }
            __syncthreads();   // vmcnt drain + barrier: tiles visible

            #pragma unroll
            for (int ks = 0; ks < 4; ++ks) {
                const int c0 = ks * 8 + k8 * 2;            // even unit index
                const int Rb = (wave & 3) * 16 + n16;
                const float4 B0 = *(const float4*)(Bs + 4 * (Rb * 32 + ((c0    ) ^ (Rb & 7))));
                const float4 B1 = *(const float4*)(Bs + 4 * (Rb * 32 + ((c0 + 1) ^ (Rb & 7))));
                const int Ra = mtile * 16 + n16;
                const float4 A0 = *(const float4*)(As + 4 * (Ra * 32 + ((c0    ) ^ (Ra & 7))));
                const float4 A1 = *(const float4*)(As + 4 * (Ra * 32 + ((c0 + 1) ^ (Ra & 7))));
                acc = __builtin_amdgcn_mfma_f32_16x16x32_bf16(
                    pack8(A0, A1), pack8(B0, B1), acc, 0, 0, 0);
            }
        }
        // ---- epilogue: bias + swiglu (even cg = gate, odd = linear) ----
        #pragma unroll
        for (int q = 0; q < 4; ++q) {
            const float val = acc[q] + bv;
            const float other = __shfl_xor(val, 1);       // partner column
            const int mrow = g0 + mtile * 16 + k8 * 4 + q;  // D: row=(l>>4)*4+q
            if ((cg & 1) == 0 && mrow < ne) {
                const float g = fminf(val, 7.0f);
                const float l = fminf(fmaxf(other, -7.0f), 7.0f);
                const float h = g / (1.0f + expf(-1.702f * g)) * (l + 1.0f);
                const int p = lst[mrow];
                hbuf[(size_t)p * MOE_I + (cg >> 1)] = f2bf_rtne(h);
            }
        }
    }
}

// ---- mlp2 (MFMA, glds, full-K): grid (8, E), 256 thr. A = hbuf bf16. ----
// Bs row-major swizzled; As bf16 [32r][16u], unit ^= row&7.
__global__ __launch_bounds__(256) void moe_mlp2(
    const u16* __restrict__ hbuf, const float* __restrict__ w2,
    const float* __restrict__ b2, const int* __restrict__ cnt,
    const int* __restrict__ lists, float* __restrict__ po) {
    __shared__ float Bs[2048 * 4];   // 32 KB
    __shared__ u16 As[512 * 8];      // 8 KB
    const int e = blockIdx.y;
    const int ne = cnt[e];
    if (ne == 0) return;
    const int tid  = threadIdx.x;
    const int lane = tid & 63;
    const int wave = tid >> 6;
    const int n16  = lane & 15;
    const int k8   = lane >> 4;
    const int* lst = lists + e * MOE_CAP;
    const int c = blockIdx.x * 64 + wave * 16 + n16;       // out col 0..511
    const float bv = b2[e * MOE_H + c];
    const float* wbase = w2 + ((size_t)e * MOE_H + blockIdx.x * 64) * MOE_I;

    for (int g0 = 0; g0 < ne; g0 += 32) {
        f32x4 acc0 = {0.f, 0.f, 0.f, 0.f};
        f32x4 acc1 = {0.f, 0.f, 0.f, 0.f};
        for (int kc = 0; kc < 4; ++kc) {
            __syncthreads();
            #pragma unroll
            for (int j = 0; j < 8; ++j) {
                const int u = (j * 4 + wave) * 64 + lane;
                const int r = u >> 5;
                const int cu = u & 31;
                GLDS16(wbase + (size_t)r * MOE_I + kc * 128 + 4 * (cu ^ (r & 7)),
                       Bs + (size_t)(j * 4 + wave) * 256);
            }
            #pragma unroll
            for (int j = 0; j < 2; ++j) {
                const int u = (j * 4 + wave) * 64 + lane;
                const int r = u >> 4;          // 0..31
                const int cu = u & 15;
                const int pm = lst[min(g0 + r, ne - 1)];
                GLDS16(hbuf + (size_t)pm * MOE_I + kc * 128 + 8 * (cu ^ (r & 7)),
                       As + (size_t)(j * 4 + wave) * 512);
            }
            __syncthreads();

            #pragma unroll
            for (int ks = 0; ks < 4; ++ks) {
                const int c0 = ks * 8 + k8 * 2;
                const int Rb = wave * 16 + n16;
                const float4 B0 = *(const float4*)(Bs + 4 * (Rb * 32 + ((c0    ) ^ (Rb & 7))));
                const float4 B1 = *(const float4*)(Bs + 4 * (Rb * 32 + ((c0 + 1) ^ (Rb & 7))));
                const s16x8 BF = pack8(B0, B1);
                const int cA = ks * 4 + k8;                // bf16 16B-unit index
                const int Ra0 = n16;
                const int Ra1 = 16 + n16;
                const s16x8 A0 = *(const s16x8*)(As + (size_t)(Ra0 * 16 + (cA ^ (Ra0 & 7))) * 8);
                const s16x8 A1 = *(const s16x8*)(As + (size_t)(Ra1 * 16 + (cA ^ (Ra1 & 7))) * 8);
                acc0 = __builtin_amdgcn_mfma_f32_16x16x32_bf16(A0, BF, acc0, 0, 0, 0);
                acc1 = __builtin_amdgcn_mfma_f32_16x16x32_bf16(A1, BF, acc1, 0, 0, 0);
            }
        }
        #pragma unroll
        for (int tile = 0; tile < 2; ++tile) {
            const f32x4 acc = tile ? acc1 : acc0;
            #pragma unroll
            for (int q = 0; q < 4; ++q) {
                const int mrow = g0 + tile * 16 + k8 * 4 + q;
                if (mrow < ne) {
                    const int p = lst[mrow];
                    po[(size_t)p * MOE_H + c] = acc[q] + bv;
                }
            }
        }
    }
}

// ---- combine: out[t,c] = ew0*po[2t,c] + ew1*po[2t+1,c] ----
__global__ __launch_bounds__(256) void MoEMLPFused_74191265071207_kernel(
    const float* __restrict__ po, const float* __restrict__ ew,
    float* __restrict__ out) {
    const int o = blockIdx.x * 256 + threadIdx.x;   // < 262144
    const int t = o >> 9;
    const int c = o & 511;
    out[o] = ew[2 * t + 0] * po[(size_t)(2 * t + 0) * MOE_H + c]
           + ew[2 * t + 1] * po[(size_t)(2 * t + 1) * MOE_H + c];
}

extern "C" void kernel_launch(void* const* d_in, const int* in_sizes, int n_in,
                              void* d_out, int out_size, void* d_ws, size_t ws_size,
                              hipStream_t stream) {
    const float* x   = (const float*)d_in[0];
    const int*   idx = (const int*)d_in[1];
    const float* ew  = (const float*)d_in[2];
    const float* w1  = (const float*)d_in[3];
    const float* b1  = (const float*)d_in[4];
    const float* w2  = (const float*)d_in[5];
    const float* b2  = (const float*)d_in[6];
    float* out = (float*)d_out;

    // ws: cnt 256B | lists 128KB | hbuf bf16 1MB | po f32 2MB  (~3.2MB)
    char* ws = (char*)d_ws;
    int* cnt   = (int*)ws;
    int* lists = (int*)(ws + 256);
    u16* hbuf  = (u16*)(ws + 256 + MOE_E * MOE_CAP * 4);
    float* po  = (float*)((char*)hbuf + (size_t)MOE_CAP * MOE_I * 2);

    moe_route<<<1, 1024, 0, stream>>>(idx, cnt, lists);
    moe_mlp1<<<dim3(16, MOE_E), 512, 0, stream>>>(x, w1, b1, cnt, lists, hbuf);
    moe_mlp2<<<dim3(8, MOE_E), 256, 0, stream>>>(hbuf, w2, b2, cnt, lists, po);
    MoEMLPFused_74191265071207_kernel<<<(512 * MOE_H) / 256, 256, 0, stream>>>(
        po, ew, out);
}